// Round 6
// baseline (7869.993 us; speedup 1.0000x reference)
//
#include <hip/hip_runtime.h>
#include <cstdint>
#include <cstddef>

#define T_STEPS 2048
#define BATCH   32
#define VDIM    512
#define HDIM    512
#define SLICES  8      // WGs per batch element
#define COLS    64     // columns owned per WG

typedef _Float16 half2v __attribute__((ext_vector_type(2)));
typedef _Float16 half8v __attribute__((ext_vector_type(8)));

__device__ __forceinline__ float dot2h(half2v a, half2v b, float c) {
#if __has_builtin(__builtin_amdgcn_fdot2)
    return __builtin_amdgcn_fdot2(a, b, c, false);
#else
    return fmaf((float)a.x, (float)b.x, fmaf((float)a.y, (float)b.y, c));
#endif
}

__device__ __forceinline__ unsigned long long loadt(const unsigned long long* p) {
    return __hip_atomic_load(p, __ATOMIC_RELAXED, __HIP_MEMORY_SCOPE_AGENT);
}
__device__ __forceinline__ void storet(unsigned long long* p, unsigned long long x) {
    __hip_atomic_store(p, x, __ATOMIC_RELAXED, __HIP_MEMORY_SCOPE_AGENT);
}

// ---------------- Phase 1: x-projection GEMM (unchanged, known-good) ----
__global__ __launch_bounds__(256)
void xproj_gemm(const float* __restrict__ X,
                const float* __restrict__ W0, const float* __restrict__ b0,
                const float* __restrict__ W1, const float* __restrict__ b1,
                const float* __restrict__ W2, const float* __restrict__ b2,
                float* __restrict__ xp, int M)
{
    const int g = blockIdx.z;
    const float* W    = (g == 0) ? W0 : (g == 1) ? W1 : W2;
    const float* bias = (g == 0) ? b0 : (g == 1) ? b1 : b2;
    float* out = xp + (size_t)g * M * HDIM;

    __shared__ float As[16][68];
    __shared__ float Bs[16][64];

    const int tid = threadIdx.x;
    const int tx = tid & 15;
    const int ty = tid >> 4;
    const int row0 = blockIdx.y * 64;
    const int n0   = blockIdx.x * 64;

    const int lm = tid >> 2;
    const int lk = (tid & 3) * 4;
    const int bk = tid >> 4;
    const int bn = (tid & 15) * 4;

    float acc[4][4] = {};

    for (int k0 = 0; k0 < VDIM; k0 += 16) {
        float4 av = *(const float4*)&X[(size_t)(row0 + lm) * VDIM + k0 + lk];
        float4 bv = *(const float4*)&W[(size_t)(k0 + bk) * HDIM + n0 + bn];
        __syncthreads();
        As[lk + 0][lm] = av.x;
        As[lk + 1][lm] = av.y;
        As[lk + 2][lm] = av.z;
        As[lk + 3][lm] = av.w;
        *(float4*)&Bs[bk][bn] = bv;
        __syncthreads();
        #pragma unroll
        for (int kk = 0; kk < 16; ++kk) {
            float4 a = *(const float4*)&As[kk][ty * 4];
            float4 b = *(const float4*)&Bs[kk][tx * 4];
            float ar[4] = {a.x, a.y, a.z, a.w};
            float br[4] = {b.x, b.y, b.z, b.w};
            #pragma unroll
            for (int i = 0; i < 4; ++i)
                #pragma unroll
                for (int j = 0; j < 4; ++j)
                    acc[i][j] += ar[i] * br[j];
        }
    }

    float4 bb = *(const float4*)&bias[n0 + tx * 4];
    #pragma unroll
    for (int i = 0; i < 4; ++i) {
        const int row = row0 + ty * 4 + i;
        float4 o;
        o.x = acc[i][0] + bb.x;
        o.y = acc[i][1] + bb.y;
        o.z = acc[i][2] + bb.z;
        o.w = acc[i][3] + bb.w;
        *(float4*)&out[(size_t)row * HDIM + n0 + tx * 4] = o;
    }
}

// ---------------- Phase 2: single-exchange scan -------------------------
// Grid 256 WGs (b = blockIdx&31, s = blockIdx>>5), 512 threads.
// Per step: each WG computes u over ITS OWN 64 columns locally (full R dots),
// then N/Z PARTIALS over its k-slice for ALL 512 columns, publishes one 8-B
// packet per column {f32 pN | f16 pZ | u16 tag}, and EVERY WG redundantly
// reduces the 8 partials -> h_new for all columns. One global leg per step.
// part[] is parity-double-buffered (p = t&1): a slot written at step t is
// next overwritten at t+2, by which time all consumers provably passed it.
__global__ __launch_bounds__(512)
__attribute__((amdgpu_waves_per_eu(2, 2)))
void gru_scan5(const float* __restrict__ xp,
               const float* __restrict__ Wrh, const float* __restrict__ Wnh,
               const float* __restrict__ Wzh,
               const float* __restrict__ state, float* __restrict__ out,
               unsigned long long* __restrict__ part,   // [2][SLICES][BATCH][HDIM]
               unsigned long long* __restrict__ hC,     // [BATCH][HDIM] chunk carry
               int t0, int nt, int M)
{
    const int b   = blockIdx.x & (BATCH - 1);
    const int s   = blockIdx.x >> 5;
    const int tid = threadIdx.x;
    const int c   = tid & (COLS - 1);
    const int j   = tid >> 6;

    __shared__ __align__(16) _Float16 hlds[HDIM];
    __shared__ __align__(16) _Float16 ulds[COLS];
    __shared__ float redR[SLICES][COLS];

    // ---- one-time: weights -> f16x2 registers (96 VGPRs total) ----
    // w2r: Wr[k in Kj][col = s*64+c]   (full-dot R for own columns)
    // w2n/w2z: Wn/Wz[k in Ks][col = tid] (k-slice partials for ALL columns)
    half2v w2r[32], w2n[32], w2z[32];
    {
        const float* pr = Wrh + (size_t)(j * 64) * HDIM + (s * COLS + c);
        const float* pn = Wnh + (size_t)(s * 64) * HDIM + tid;
        const float* pz = Wzh + (size_t)(s * 64) * HDIM + tid;
        #pragma unroll
        for (int q = 0; q < 32; ++q) {
            half2v r, nn, z;
            r.x  = (_Float16)pr[(size_t)(2 * q) * HDIM];
            r.y  = (_Float16)pr[(size_t)(2 * q + 1) * HDIM];
            nn.x = (_Float16)pn[(size_t)(2 * q) * HDIM];
            nn.y = (_Float16)pn[(size_t)(2 * q + 1) * HDIM];
            z.x  = (_Float16)pz[(size_t)(2 * q) * HDIM];
            z.y  = (_Float16)pz[(size_t)(2 * q + 1) * HDIM];
            w2r[q] = r; w2n[q] = nn; w2z[q] = z;
        }
        #pragma unroll
        for (int q = 0; q < 32; ++q)
            asm volatile("" : "+v"(w2r[q]), "+v"(w2n[q]), "+v"(w2z[q]));
    }

    const size_t bb = (size_t)b * HDIM;
    const size_t gs = (size_t)M * HDIM;
    const size_t pstride = (size_t)BATCH * HDIM;      // between producer slices

    // ---- init own-column h (fp32 register, carried across all steps) ----
    float hreg;
    if (t0 == 0) {
        hreg = state[bb + tid];
    } else {
        unsigned long long v = loadt(hC + bb + tid);
        while ((unsigned)(v & 0xFFFFu) != (unsigned)(t0 & 0xFFFF))
            v = loadt(hC + bb + tid);
        hreg = __uint_as_float((unsigned)(v >> 32));
    }
    hlds[tid] = (_Float16)hreg;
    __syncthreads();

    for (int tt = 0; tt < nt; ++tt) {
        const int t = t0 + tt;
        const int p = t & 1;
        const unsigned want = (unsigned)((t + 1) & 0xFFFF);

        // xp prefetch (own column; independent of everything below)
        const size_t rb = ((size_t)tt * BATCH + b) * HDIM;
        float xr = 0.f;
        if (j == s) xr = xp[rb + tid];
        const float xnn = xp[gs + rb + tid];
        const float xz  = xp[2 * gs + rb + tid];

        // ---- R partials: column s*64+c over k-range of wave j ----
        {
            float aR = 0.f;
            const half8v* hp = (const half8v*)&hlds[j * 64];
            #pragma unroll
            for (int q = 0; q < 8; ++q) {
                half8v h8 = hp[q];
                half2v p0 = {h8[0], h8[1]}, p1 = {h8[2], h8[3]};
                half2v p2 = {h8[4], h8[5]}, p3 = {h8[6], h8[7]};
                aR = dot2h(p0, w2r[4 * q + 0], aR);
                aR = dot2h(p1, w2r[4 * q + 1], aR);
                aR = dot2h(p2, w2r[4 * q + 2], aR);
                aR = dot2h(p3, w2r[4 * q + 3], aR);
            }
            redR[j][c] = aR;
        }
        __syncthreads();                                   // A

        // ---- wave s: u over own columns (fp32 h from hreg) ----
        if (j == s) {
            float sR = 0.f;
            #pragma unroll
            for (int jj = 0; jj < SLICES; ++jj) sR += redR[jj][c];
            float R = 1.f / (1.f + __expf(-(xr + sR)));
            ulds[c] = (_Float16)(hreg * R);
        }
        __syncthreads();                                   // B

        // ---- N,Z partials over own k-slice for column tid; publish packet ----
        {
            float aN = 0.f, aZ = 0.f;
            const half8v* up = (const half8v*)ulds;
            #pragma unroll
            for (int q = 0; q < 8; ++q) {
                half8v u8 = up[q];
                half2v p0 = {u8[0], u8[1]}, p1 = {u8[2], u8[3]};
                half2v p2 = {u8[4], u8[5]}, p3 = {u8[6], u8[7]};
                aN = dot2h(p0, w2n[4 * q + 0], aN);
                aZ = dot2h(p0, w2z[4 * q + 0], aZ);
                aN = dot2h(p1, w2n[4 * q + 1], aN);
                aZ = dot2h(p1, w2z[4 * q + 1], aZ);
                aN = dot2h(p2, w2n[4 * q + 2], aN);
                aZ = dot2h(p2, w2z[4 * q + 2], aZ);
                aN = dot2h(p3, w2n[4 * q + 3], aN);
                aZ = dot2h(p3, w2z[4 * q + 3], aZ);
            }
            union { unsigned short u; _Float16 h; } zc; zc.h = (_Float16)aZ;
            unsigned long long pkt = ((unsigned long long)__float_as_uint(aN) << 32)
                                   | ((unsigned long long)zc.u << 16) | want;
            storet(part + ((size_t)p * SLICES + s) * pstride + bb + tid, pkt);
        }

        // ---- poll all 8 producers' partials for own column (parallel loads) ----
        unsigned long long pk[SLICES];
        {
            unsigned long long* pbase = part + (size_t)p * SLICES * pstride + bb + tid;
            #pragma unroll
            for (int ss = 0; ss < SLICES; ++ss)
                pk[ss] = loadt(pbase + (size_t)ss * pstride);
            #pragma unroll
            for (int ss = 0; ss < SLICES; ++ss)
                while ((unsigned)(pk[ss] & 0xFFFFu) != want)
                    pk[ss] = loadt(pbase + (size_t)ss * pstride);
        }

        // ---- redundant reduce + blend: every WG computes h_new[tid] ----
        {
            float sN = 0.f, sZ = 0.f;
            #pragma unroll
            for (int ss = 0; ss < SLICES; ++ss) {
                sN += __uint_as_float((unsigned)(pk[ss] >> 32));
                union { unsigned short u; _Float16 h; } zc;
                zc.u = (unsigned short)(pk[ss] >> 16);
                sZ += (float)zc.h;
            }
            float e  = __expf(2.f * (xnn + sN));
            float Hc = 1.f - 2.f / (e + 1.f);              // tanh
            float Z  = 1.f / (1.f + __expf(-(xz + sZ)));
            float hnew = Z * hreg + (1.f - Z) * Hc;
            hreg = hnew;
            hlds[tid] = (_Float16)hnew;

            if (j == s) {                                  // owner writes output
                __builtin_nontemporal_store(hnew, out + (size_t)t * BATCH * HDIM + bb + tid);
                if (t == T_STEPS - 1)
                    out[(size_t)T_STEPS * BATCH * HDIM + bb + tid] = hnew;
                if (tt == nt - 1)                          // chunk carry (cold path)
                    storet(hC + bb + tid,
                           ((unsigned long long)__float_as_uint(hnew) << 32) | want);
            }
        }
        __syncthreads();                                   // C: hlds ready for next R
    }
}

extern "C" void kernel_launch(void* const* d_in, const int* in_sizes, int n_in,
                              void* d_out, int out_size, void* d_ws, size_t ws_size,
                              hipStream_t stream) {
    const float* inputs   = (const float*)d_in[0];
    const float* state    = (const float*)d_in[1];
    const float* W_reset  = (const float*)d_in[2];
    const float* b_reset  = (const float*)d_in[3];
    const float* W_net    = (const float*)d_in[4];
    const float* b_net    = (const float*)d_in[5];
    const float* W_update = (const float*)d_in[6];
    const float* b_update = (const float*)d_in[7];
    float* out = (float*)d_out;

    // tail: part[2][8][32][512] u64 (2 MB) + hC[32][512] u64 (128 KB)
    const size_t buf_elems  = (size_t)BATCH * HDIM;
    const size_t part_elems = 2ull * SLICES * buf_elems;
    const size_t tail_bytes = (part_elems + buf_elems) * 8;
    size_t tail_base = (ws_size - tail_bytes) & ~(size_t)255;
    char* base = (char*)d_ws;
    float* xp = (float*)base;
    unsigned long long* part = (unsigned long long*)(base + tail_base);
    unsigned long long* hC   = part + part_elems;

    const size_t per_t = 3ull * BATCH * HDIM * sizeof(float);
    int C = (int)(tail_base / per_t);
    if (C > T_STEPS) C = T_STEPS;
    C &= ~1;
    if (C < 2) C = 2;

    // wipe tags each call (0xFFFF never matches a step tag) -> deterministic replays
    hipMemsetAsync(part, 0xFF, tail_bytes, stream);

    for (int t0 = 0; t0 < T_STEPS; t0 += C) {
        const int nt = (T_STEPS - t0 < C) ? (T_STEPS - t0) : C;
        const int M  = nt * BATCH;

        dim3 g1(HDIM / 64, M / 64, 3);
        xproj_gemm<<<g1, 256, 0, stream>>>(inputs + (size_t)t0 * BATCH * VDIM,
                                           W_reset, b_reset,
                                           W_net,   b_net,
                                           W_update, b_update,
                                           xp, M);

        gru_scan5<<<BATCH * SLICES, 512, 0, stream>>>(
            xp,
            W_reset  + (size_t)VDIM * HDIM,
            W_net    + (size_t)VDIM * HDIM,
            W_update + (size_t)VDIM * HDIM,
            state, out, part, hC, t0, nt, M);
    }
}

// Round 7
// 5461.299 us; speedup vs baseline: 1.4410x; 1.4410x over previous
//
#include <hip/hip_runtime.h>
#include <cstdint>
#include <cstddef>

#define T_STEPS 2048
#define BATCH   32
#define VDIM    512
#define HDIM    512
#define SLICES  8      // WGs per batch element (scan)
#define COLS    64     // columns per scan WG
#define KPT     64     // k-range per scan wave
#define BM      128    // GEMM rows per WG
#define BN      64     // GEMM cols per WG

typedef _Float16 half2v __attribute__((ext_vector_type(2)));
typedef _Float16 half8v __attribute__((ext_vector_type(8)));
typedef float    f32x4  __attribute__((ext_vector_type(4)));

__device__ __forceinline__ float dot2h(half2v a, half2v b, float c) {
#if __has_builtin(__builtin_amdgcn_fdot2)
    return __builtin_amdgcn_fdot2(a, b, c, false);
#else
    return fmaf((float)a.x, (float)b.x, fmaf((float)a.y, (float)b.y, c));
#endif
}

__device__ __forceinline__ unsigned long long loadt(const unsigned long long* p) {
    return __hip_atomic_load(p, __ATOMIC_RELAXED, __HIP_MEMORY_SCOPE_AGENT);
}
__device__ __forceinline__ void storet(unsigned long long* p, float v, unsigned tag) {
    unsigned long long x = ((unsigned long long)tag << 32) | (unsigned)__float_as_uint(v);
    __hip_atomic_store(p, x, __ATOMIC_RELAXED, __HIP_MEMORY_SCOPE_AGENT);
}

// ---------------- Phase 1: x-projection GEMM via f16 MFMA ----------------
// xp[g][m][n] = X[m][:512] @ Wg[0:512][n] + bg[n], f32 accum/output.
// Tile 128x64, 4 waves; B (full K) staged once in LDS as [kg][col][8] half8.
// Grid.x = (n-tile | g) fastest-varying so WGs sharing A rows co-run (L2 reuse).
__global__ __launch_bounds__(256)
void xproj_mfma(const float* __restrict__ X,
                const float* __restrict__ W0, const float* __restrict__ b0,
                const float* __restrict__ W1, const float* __restrict__ b1,
                const float* __restrict__ W2, const float* __restrict__ b2,
                float* __restrict__ xp, int M)
{
    const int g  = blockIdx.x >> 3;
    const int n0 = (blockIdx.x & 7) * BN;
    const int m0 = blockIdx.y * BM;
    const float* W    = (g == 0) ? W0 : (g == 1) ? W1 : W2;
    const float* bias = (g == 0) ? b0 : (g == 1) ? b1 : b2;
    float* out = xp + (size_t)g * M * HDIM;

    __shared__ __align__(16) _Float16 Blds[64 * 64 * 8];  // 64 KB

    const int tid  = threadIdx.x;
    const int lane = tid & 63;
    const int w    = tid >> 6;        // wave 0..3 -> rows [32w, 32w+32)
    const int r16  = lane & 15;
    const int kq   = lane >> 4;       // k-quarter 0..3

    // ---- stage B[512][64] -> f16 LDS, once (no k-loop barriers needed) ----
    {
        const int c = tid & 63;
        #pragma unroll
        for (int it = 0; it < 16; ++it) {
            const int kg = (tid >> 6) + 4 * it;
            const float* src = W + (size_t)(kg * 8) * HDIM + n0 + c;
            half8v v;
            #pragma unroll
            for (int i = 0; i < 8; ++i) v[i] = (_Float16)src[(size_t)i * HDIM];
            *(half8v*)&Blds[(size_t)(kg * 64 + c) * 8] = v;
        }
    }
    __syncthreads();

    f32x4 acc[2][4] = {};             // [m-sub 16][n-frag 16]

    for (int ks = 0; ks < 16; ++ks) {
        const int kg = 4 * ks + kq;   // 8-wide k-group for this lane
        half8v a[2];
        #pragma unroll
        for (int ms = 0; ms < 2; ++ms) {
            const float* ap = X + (size_t)(m0 + 32 * w + 16 * ms + r16) * VDIM + kg * 8;
            float4 a0 = *(const float4*)ap;
            float4 a1 = *(const float4*)(ap + 4);
            a[ms][0] = (_Float16)a0.x; a[ms][1] = (_Float16)a0.y;
            a[ms][2] = (_Float16)a0.z; a[ms][3] = (_Float16)a0.w;
            a[ms][4] = (_Float16)a1.x; a[ms][5] = (_Float16)a1.y;
            a[ms][6] = (_Float16)a1.z; a[ms][7] = (_Float16)a1.w;
        }
        #pragma unroll
        for (int cb = 0; cb < 4; ++cb) {
            half8v bf = *(const half8v*)&Blds[(size_t)(kg * 64 + 16 * cb + r16) * 8];
            acc[0][cb] = __builtin_amdgcn_mfma_f32_16x16x32_f16(a[0], bf, acc[0][cb], 0, 0, 0);
            acc[1][cb] = __builtin_amdgcn_mfma_f32_16x16x32_f16(a[1], bf, acc[1][cb], 0, 0, 0);
        }
    }

    // ---- epilogue: D row = 4*kq + r, col = r16 (m89-verified mapping) ----
    #pragma unroll
    for (int cb = 0; cb < 4; ++cb) {
        const float bb = bias[n0 + 16 * cb + r16];
        #pragma unroll
        for (int ms = 0; ms < 2; ++ms)
            #pragma unroll
            for (int r = 0; r < 4; ++r) {
                const int row = m0 + 32 * w + 16 * ms + 4 * kq + r;
                out[(size_t)row * HDIM + n0 + 16 * cb + r16] = acc[ms][cb][r] + bb;
            }
    }
}

// ---------------- Phase 2: scan (R4-verbatim: verified best, 2.64 us/step) ----
__global__ __launch_bounds__(512)
__attribute__((amdgpu_waves_per_eu(2, 2)))
void gru_scan3(const float* __restrict__ xp,
               const float* __restrict__ Wrh, const float* __restrict__ Wnh,
               const float* __restrict__ Wzh,
               const float* __restrict__ state, float* __restrict__ out,
               unsigned long long* __restrict__ hT,
               unsigned long long* __restrict__ uT,
               int t0, int nt, int M)
{
    const int b   = blockIdx.x & (BATCH - 1);
    const int s   = blockIdx.x >> 5;
    const int tid = threadIdx.x;
    const int c   = tid & (COLS - 1);
    const int j   = tid >> 6;
    const int n   = s * COLS + c;

    __shared__ __align__(16) _Float16 hlds[HDIM];
    __shared__ __align__(16) _Float16 ulds[HDIM];
    __shared__ float redR[SLICES][COLS];
    __shared__ float redN[SLICES][COLS];
    __shared__ float redZ[SLICES][COLS];

    half2v w2r[KPT / 2], w2n[KPT / 2], w2z[KPT / 2];
    {
        const size_t coloff = (size_t)s * COLS + c;
        const float* pr = Wrh + (size_t)j * KPT * HDIM + coloff;
        const float* pn = Wnh + (size_t)j * KPT * HDIM + coloff;
        const float* pz = Wzh + (size_t)j * KPT * HDIM + coloff;
        #pragma unroll
        for (int q = 0; q < KPT / 2; ++q) {
            half2v r, nn, z;
            r.x  = (_Float16)pr[(size_t)(2 * q) * HDIM];
            r.y  = (_Float16)pr[(size_t)(2 * q + 1) * HDIM];
            nn.x = (_Float16)pn[(size_t)(2 * q) * HDIM];
            nn.y = (_Float16)pn[(size_t)(2 * q + 1) * HDIM];
            z.x  = (_Float16)pz[(size_t)(2 * q) * HDIM];
            z.y  = (_Float16)pz[(size_t)(2 * q + 1) * HDIM];
            w2r[q] = r; w2n[q] = nn; w2z[q] = z;
        }
        #pragma unroll
        for (int q = 0; q < KPT / 2; ++q)
            asm volatile("" : "+v"(w2r[q]), "+v"(w2n[q]), "+v"(w2z[q]));
    }

    const size_t bb32 = (size_t)b * HDIM;
    unsigned long long* hTb = hT + bb32;
    unsigned long long* uTb = uT + bb32;
    const size_t gs = (size_t)M * HDIM;

    for (int tt = 0; tt < nt; ++tt) {
        const int t = t0 + tt;

        float xr = 0.f, xnn = 0.f, xz = 0.f;
        const size_t rb = ((size_t)tt * BATCH + b) * HDIM;
        if (tid < COLS) {
            xr  = xp[rb + n];
            xnn = xp[gs + rb + n];
            xz  = xp[2 * gs + rb + n];
        }

        float hv, hcv = 0.f;
        if (t == 0) {
            hv = state[bb32 + tid];
            if (tid < COLS) hcv = state[bb32 + n];
        } else {
            unsigned long long v;
            do { v = loadt(hTb + tid); } while ((unsigned)(v >> 32) != (unsigned)t);
            hv = __uint_as_float((unsigned)v);
            if (tid < COLS) {
                do { v = loadt(hTb + n); } while ((unsigned)(v >> 32) != (unsigned)t);
                hcv = __uint_as_float((unsigned)v);
            }
        }

        hlds[tid] = (_Float16)hv;
        asm volatile("s_waitcnt lgkmcnt(0)" ::: "memory");
        __builtin_amdgcn_sched_barrier(0);

        {
            float aR = 0.f;
            const half8v* hp = (const half8v*)&hlds[j * KPT];
            #pragma unroll
            for (int q = 0; q < KPT / 8; ++q) {
                half8v h8 = hp[q];
                half2v p0 = {h8[0], h8[1]}, p1 = {h8[2], h8[3]};
                half2v p2 = {h8[4], h8[5]}, p3 = {h8[6], h8[7]};
                aR = dot2h(p0, w2r[4 * q + 0], aR);
                aR = dot2h(p1, w2r[4 * q + 1], aR);
                aR = dot2h(p2, w2r[4 * q + 2], aR);
                aR = dot2h(p3, w2r[4 * q + 3], aR);
            }
            redR[j][c] = aR;
        }
        __syncthreads();

        if (tid < COLS) {
            float sR = 0.f;
            #pragma unroll
            for (int jj = 0; jj < SLICES; ++jj) sR += redR[jj][c];
            float R = 1.f / (1.f + __expf(-(xr + sR)));
            storet(uTb + n, hcv * R, (unsigned)(t + 1));
        }

        {
            unsigned long long v;
            do { v = loadt(uTb + tid); } while ((unsigned)(v >> 32) != (unsigned)(t + 1));
            ulds[tid] = (_Float16)__uint_as_float((unsigned)v);
        }
        asm volatile("s_waitcnt lgkmcnt(0)" ::: "memory");
        __builtin_amdgcn_sched_barrier(0);

        {
            float aN = 0.f, aZ = 0.f;
            const half8v* up = (const half8v*)&ulds[j * KPT];
            #pragma unroll
            for (int q = 0; q < KPT / 8; ++q) {
                half8v u8 = up[q];
                half2v p0 = {u8[0], u8[1]}, p1 = {u8[2], u8[3]};
                half2v p2 = {u8[4], u8[5]}, p3 = {u8[6], u8[7]};
                aN = dot2h(p0, w2n[4 * q + 0], aN);
                aZ = dot2h(p0, w2z[4 * q + 0], aZ);
                aN = dot2h(p1, w2n[4 * q + 1], aN);
                aZ = dot2h(p1, w2z[4 * q + 1], aZ);
                aN = dot2h(p2, w2n[4 * q + 2], aN);
                aZ = dot2h(p2, w2z[4 * q + 2], aZ);
                aN = dot2h(p3, w2n[4 * q + 3], aN);
                aZ = dot2h(p3, w2z[4 * q + 3], aZ);
            }
            redN[j][c] = aN;
            redZ[j][c] = aZ;
        }
        __syncthreads();

        if (tid < COLS) {
            float sN = 0.f, sZ = 0.f;
            #pragma unroll
            for (int jj = 0; jj < SLICES; ++jj) { sN += redN[jj][c]; sZ += redZ[jj][c]; }
            float e  = __expf(2.f * (xnn + sN));
            float Hc = 1.f - 2.f / (e + 1.f);
            float Z  = 1.f / (1.f + __expf(-(xz + sZ)));
            float hnew = Z * hcv + (1.f - Z) * Hc;
            __builtin_nontemporal_store(hnew, out + (size_t)t * BATCH * HDIM + bb32 + n);
            storet(hTb + n, hnew, (unsigned)(t + 1));
            if (t == T_STEPS - 1)
                out[(size_t)T_STEPS * BATCH * HDIM + bb32 + n] = hnew;
        }
    }
}

extern "C" void kernel_launch(void* const* d_in, const int* in_sizes, int n_in,
                              void* d_out, int out_size, void* d_ws, size_t ws_size,
                              hipStream_t stream) {
    const float* inputs   = (const float*)d_in[0];
    const float* state    = (const float*)d_in[1];
    const float* W_reset  = (const float*)d_in[2];
    const float* b_reset  = (const float*)d_in[3];
    const float* W_net    = (const float*)d_in[4];
    const float* b_net    = (const float*)d_in[5];
    const float* W_update = (const float*)d_in[6];
    const float* b_update = (const float*)d_in[7];
    float* out = (float*)d_out;

    // tail: tagged h + tagged u = 2 * 32*512*8 B = 256 KB
    const size_t tail_bytes = 2ull * BATCH * HDIM * 8;
    size_t tail_base = (ws_size - tail_bytes) & ~(size_t)255;
    char* base = (char*)d_ws;
    float* xp = (float*)base;
    unsigned long long* hT = (unsigned long long*)(base + tail_base);
    unsigned long long* uT = hT + (size_t)BATCH * HDIM;

    const size_t per_t = 3ull * BATCH * HDIM * sizeof(float);
    int C = (int)(tail_base / per_t);
    if (C > T_STEPS) C = T_STEPS;
    C &= ~3;                       // M = nt*32 must be divisible by BM=128
    if (C < 4) C = 4;

    hipMemsetAsync(hT, 0xFF, tail_bytes, stream);

    for (int t0 = 0; t0 < T_STEPS; t0 += C) {
        const int nt = (T_STEPS - t0 < C) ? (T_STEPS - t0) : C;
        const int M  = nt * BATCH;

        dim3 g1(8 * 3, M / BM);    // (n-tile | g) fastest -> A-row L2 sharing
        xproj_mfma<<<g1, 256, 0, stream>>>(inputs + (size_t)t0 * BATCH * VDIM,
                                           W_reset, b_reset,
                                           W_net,   b_net,
                                           W_update, b_update,
                                           xp, M);

        gru_scan3<<<BATCH * SLICES, 512, 0, stream>>>(
            xp,
            W_reset  + (size_t)VDIM * HDIM,
            W_net    + (size_t)VDIM * HDIM,
            W_update + (size_t)VDIM * HDIM,
            state, out, hT, uT, t0, nt, M);
    }
}

// Round 8
// 5298.558 us; speedup vs baseline: 1.4853x; 1.0307x over previous
//
#include <hip/hip_runtime.h>
#include <cstdint>
#include <cstddef>

#define T_STEPS 2048
#define BATCH   32
#define VDIM    512
#define HDIM    512
#define SLICES  8      // WGs per batch element (scan)
#define COLS    64     // columns per scan WG
#define KPT     64     // k-range per scan wave
#define BM      128    // GEMM rows per WG
#define BN      64     // GEMM cols per WG

typedef _Float16 half2v __attribute__((ext_vector_type(2)));
typedef _Float16 half8v __attribute__((ext_vector_type(8)));
typedef float    f32x4  __attribute__((ext_vector_type(4)));

__device__ __forceinline__ float dot2h(half2v a, half2v b, float c) {
#if __has_builtin(__builtin_amdgcn_fdot2)
    return __builtin_amdgcn_fdot2(a, b, c, false);
#else
    return fmaf((float)a.x, (float)b.x, fmaf((float)a.y, (float)b.y, c));
#endif
}

__device__ __forceinline__ unsigned long long loadt(const unsigned long long* p) {
    return __hip_atomic_load(p, __ATOMIC_RELAXED, __HIP_MEMORY_SCOPE_AGENT);
}
__device__ __forceinline__ void storet(unsigned long long* p, float v, unsigned tag) {
    unsigned long long x = ((unsigned long long)tag << 32) | (unsigned)__float_as_uint(v);
    __hip_atomic_store(p, x, __ATOMIC_RELAXED, __HIP_MEMORY_SCOPE_AGENT);
}

// ---------------- Phase 0: pack W -> k-packed f16 tiles (once per call) ----
// Bt[g][kg][n][i] = (f16) Wg[kg*8+i][n];  g<3, kg<64, n<512, i<8.
// Reads coalesced across n (lane = n); writes 16 B/lane contiguous.
__global__ __launch_bounds__(512)
void pack_b(const float* __restrict__ W0, const float* __restrict__ W1,
            const float* __restrict__ W2, _Float16* __restrict__ Bt)
{
    const int kg = blockIdx.x;                 // 0..63
    const int g  = blockIdx.y;                 // 0..2
    const float* W = (g == 0) ? W0 : (g == 1) ? W1 : W2;
    const int n = threadIdx.x;                 // 0..511
    half8v v;
    #pragma unroll
    for (int i = 0; i < 8; ++i)
        v[i] = (_Float16)W[(size_t)(kg * 8 + i) * HDIM + n];
    *(half8v*)&Bt[((((size_t)g * 64 + kg) * 512) + n) * 8] = v;
}

// ---------------- Phase 1: fused-gate x-projection via f16 MFMA ----------
// One WG computes all 3 gates for its 128x64 tile: A f16 in regs (pinned),
// B tile coalesced-copied from packed Bt into LDS per gate. No k-loop barriers.
__global__ __launch_bounds__(256)
void xproj_mfma2(const float* __restrict__ X, const _Float16* __restrict__ Bt,
                 const float* __restrict__ b0, const float* __restrict__ b1,
                 const float* __restrict__ b2,
                 float* __restrict__ xp, int M)
{
    const int n0 = blockIdx.x * BN;
    const int m0 = blockIdx.y * BM;

    __shared__ __align__(16) _Float16 Blds[64 * 64 * 8];  // 64 KB

    const int tid  = threadIdx.x;
    const int lane = tid & 63;
    const int w    = tid >> 6;
    const int r16  = lane & 15;
    const int kq   = lane >> 4;

    // ---- A -> f16 registers, once (128 VGPRs, pinned) ----
    half8v a[2][16];
    #pragma unroll
    for (int ms = 0; ms < 2; ++ms) {
        const float* ap = X + (size_t)(m0 + 32 * w + 16 * ms + r16) * VDIM;
        #pragma unroll
        for (int ks = 0; ks < 16; ++ks) {
            const float* p = ap + ks * 32 + kq * 8;
            float4 x0 = *(const float4*)p;
            float4 x1 = *(const float4*)(p + 4);
            half8v v;
            v[0] = (_Float16)x0.x; v[1] = (_Float16)x0.y;
            v[2] = (_Float16)x0.z; v[3] = (_Float16)x0.w;
            v[4] = (_Float16)x1.x; v[5] = (_Float16)x1.y;
            v[6] = (_Float16)x1.z; v[7] = (_Float16)x1.w;
            a[ms][ks] = v;
        }
    }
    #pragma unroll
    for (int ms = 0; ms < 2; ++ms)
        #pragma unroll
        for (int ks = 0; ks < 16; ++ks)
            asm volatile("" : "+v"(a[ms][ks]));

    for (int g = 0; g < 3; ++g) {
        __syncthreads();                        // previous gate's LDS reads done
        {   // coalesced 64 KB copy: Bt[g][kg][n0+c][.] -> Blds[kg][c][.]
            const _Float16* src = Bt + (((size_t)g * 64) * 512 + n0) * 8;
            const int c = tid & 63;
            #pragma unroll
            for (int it = 0; it < 16; ++it) {
                const int kg = (tid >> 6) + 4 * it;
                *(half8v*)&Blds[(size_t)(kg * 64 + c) * 8] =
                    *(const half8v*)&src[((size_t)kg * 512 + c) * 8];
            }
        }
        __syncthreads();

        f32x4 acc[2][4] = {};
        #pragma unroll
        for (int ks = 0; ks < 16; ++ks) {
            #pragma unroll
            for (int cb = 0; cb < 4; ++cb) {
                half8v bf = *(const half8v*)
                    &Blds[(size_t)((4 * ks + kq) * 64 + 16 * cb + r16) * 8];
                acc[0][cb] = __builtin_amdgcn_mfma_f32_16x16x32_f16(a[0][ks], bf, acc[0][cb], 0, 0, 0);
                acc[1][cb] = __builtin_amdgcn_mfma_f32_16x16x32_f16(a[1][ks], bf, acc[1][cb], 0, 0, 0);
            }
        }

        const float* bias = (g == 0) ? b0 : (g == 1) ? b1 : b2;
        float* out = xp + (size_t)g * M * HDIM;
        #pragma unroll
        for (int cb = 0; cb < 4; ++cb) {
            const float bb = bias[n0 + 16 * cb + r16];
            #pragma unroll
            for (int ms = 0; ms < 2; ++ms)
                #pragma unroll
                for (int r = 0; r < 4; ++r) {
                    const int row = m0 + 32 * w + 16 * ms + 4 * kq + r;
                    out[(size_t)row * HDIM + n0 + 16 * cb + r16] = acc[ms][cb][r] + bb;
                }
        }
    }
}

// ---------------- Phase 2: scan (R4 structure + micro-opts) ----------------
// Changes vs verified gru_scan3: (1) wave0 carries own-column h in register
// (no per-step hcv poll), (2) 4-acc / 2+2-acc dot chains, (3) h published
// before output store, (4) tree partial-reduces.
__global__ __launch_bounds__(512)
__attribute__((amdgpu_waves_per_eu(2, 2)))
void gru_scan6(const float* __restrict__ xp,
               const float* __restrict__ Wrh, const float* __restrict__ Wnh,
               const float* __restrict__ Wzh,
               const float* __restrict__ state, float* __restrict__ out,
               unsigned long long* __restrict__ hT,
               unsigned long long* __restrict__ uT,
               int t0, int nt, int M)
{
    const int b   = blockIdx.x & (BATCH - 1);
    const int s   = blockIdx.x >> 5;
    const int tid = threadIdx.x;
    const int c   = tid & (COLS - 1);
    const int j   = tid >> 6;
    const int n   = s * COLS + c;

    __shared__ __align__(16) _Float16 hlds[HDIM];
    __shared__ __align__(16) _Float16 ulds[HDIM];
    __shared__ float redR[SLICES][COLS];
    __shared__ float redN[SLICES][COLS];
    __shared__ float redZ[SLICES][COLS];

    half2v w2r[KPT / 2], w2n[KPT / 2], w2z[KPT / 2];
    {
        const size_t coloff = (size_t)s * COLS + c;
        const float* pr = Wrh + (size_t)j * KPT * HDIM + coloff;
        const float* pn = Wnh + (size_t)j * KPT * HDIM + coloff;
        const float* pz = Wzh + (size_t)j * KPT * HDIM + coloff;
        #pragma unroll
        for (int q = 0; q < KPT / 2; ++q) {
            half2v r, nn, z;
            r.x  = (_Float16)pr[(size_t)(2 * q) * HDIM];
            r.y  = (_Float16)pr[(size_t)(2 * q + 1) * HDIM];
            nn.x = (_Float16)pn[(size_t)(2 * q) * HDIM];
            nn.y = (_Float16)pn[(size_t)(2 * q + 1) * HDIM];
            z.x  = (_Float16)pz[(size_t)(2 * q) * HDIM];
            z.y  = (_Float16)pz[(size_t)(2 * q + 1) * HDIM];
            w2r[q] = r; w2n[q] = nn; w2z[q] = z;
        }
        #pragma unroll
        for (int q = 0; q < KPT / 2; ++q)
            asm volatile("" : "+v"(w2r[q]), "+v"(w2n[q]), "+v"(w2z[q]));
    }

    const size_t bb32 = (size_t)b * HDIM;
    unsigned long long* hTb = hT + bb32;
    unsigned long long* uTb = uT + bb32;
    const size_t gs = (size_t)M * HDIM;

    float hcv = 0.f;                   // wave0: own-column h, register-carried

    for (int tt = 0; tt < nt; ++tt) {
        const int t = t0 + tt;

        float xr = 0.f, xnn = 0.f, xz = 0.f;
        const size_t rb = ((size_t)tt * BATCH + b) * HDIM;
        if (tid < COLS) {
            xr  = xp[rb + n];
            xnn = xp[gs + rb + n];
            xz  = xp[2 * gs + rb + n];
        }

        float hv;
        if (t == 0) {
            hv = state[bb32 + tid];
            if (tid < COLS) hcv = state[bb32 + n];
        } else {
            unsigned long long v;
            do { v = loadt(hTb + tid); } while ((unsigned)(v >> 32) != (unsigned)t);
            hv = __uint_as_float((unsigned)v);
            if (tt == 0 && tid < COLS) {   // chunk restart only: recover carry
                do { v = loadt(hTb + n); } while ((unsigned)(v >> 32) != (unsigned)t);
                hcv = __uint_as_float((unsigned)v);
            }
        }

        hlds[tid] = (_Float16)hv;
        asm volatile("s_waitcnt lgkmcnt(0)" ::: "memory");
        __builtin_amdgcn_sched_barrier(0);

        // ---- R partials: 4 independent acc chains of depth 8 ----
        {
            float a0 = 0.f, a1 = 0.f, a2 = 0.f, a3 = 0.f;
            const half8v* hp = (const half8v*)&hlds[j * KPT];
            #pragma unroll
            for (int q = 0; q < KPT / 8; ++q) {
                half8v h8 = hp[q];
                half2v p0 = {h8[0], h8[1]}, p1 = {h8[2], h8[3]};
                half2v p2 = {h8[4], h8[5]}, p3 = {h8[6], h8[7]};
                a0 = dot2h(p0, w2r[4 * q + 0], a0);
                a1 = dot2h(p1, w2r[4 * q + 1], a1);
                a2 = dot2h(p2, w2r[4 * q + 2], a2);
                a3 = dot2h(p3, w2r[4 * q + 3], a3);
            }
            redR[j][c] = (a0 + a1) + (a2 + a3);
        }
        __syncthreads();                               // barrier A

        if (tid < COLS) {
            float s01 = redR[0][c] + redR[1][c];
            float s23 = redR[2][c] + redR[3][c];
            float s45 = redR[4][c] + redR[5][c];
            float s67 = redR[6][c] + redR[7][c];
            float sR  = (s01 + s23) + (s45 + s67);
            float R = 1.f / (1.f + __expf(-(xr + sR)));
            storet(uTb + n, hcv * R, (unsigned)(t + 1));
        }

        {
            unsigned long long v;
            do { v = loadt(uTb + tid); } while ((unsigned)(v >> 32) != (unsigned)(t + 1));
            ulds[tid] = (_Float16)__uint_as_float((unsigned)v);
        }
        asm volatile("s_waitcnt lgkmcnt(0)" ::: "memory");
        __builtin_amdgcn_sched_barrier(0);

        // ---- N,Z partials: 2+2 acc chains of depth 16 ----
        {
            float aN0 = 0.f, aN1 = 0.f, aZ0 = 0.f, aZ1 = 0.f;
            const half8v* up = (const half8v*)&ulds[j * KPT];
            #pragma unroll
            for (int q = 0; q < KPT / 8; ++q) {
                half8v u8 = up[q];
                half2v p0 = {u8[0], u8[1]}, p1 = {u8[2], u8[3]};
                half2v p2 = {u8[4], u8[5]}, p3 = {u8[6], u8[7]};
                aN0 = dot2h(p0, w2n[4 * q + 0], aN0);
                aZ0 = dot2h(p0, w2z[4 * q + 0], aZ0);
                aN1 = dot2h(p1, w2n[4 * q + 1], aN1);
                aZ1 = dot2h(p1, w2z[4 * q + 1], aZ1);
                aN0 = dot2h(p2, w2n[4 * q + 2], aN0);
                aZ0 = dot2h(p2, w2z[4 * q + 2], aZ0);
                aN1 = dot2h(p3, w2n[4 * q + 3], aN1);
                aZ1 = dot2h(p3, w2z[4 * q + 3], aZ1);
            }
            redN[j][c] = aN0 + aN1;
            redZ[j][c] = aZ0 + aZ1;
        }
        __syncthreads();                               // barrier B

        if (tid < COLS) {
            float n01 = redN[0][c] + redN[1][c], n23 = redN[2][c] + redN[3][c];
            float n45 = redN[4][c] + redN[5][c], n67 = redN[6][c] + redN[7][c];
            float z01 = redZ[0][c] + redZ[1][c], z23 = redZ[2][c] + redZ[3][c];
            float z45 = redZ[4][c] + redZ[5][c], z67 = redZ[6][c] + redZ[7][c];
            float sN = (n01 + n23) + (n45 + n67);
            float sZ = (z01 + z23) + (z45 + z67);
            float e  = __expf(2.f * (xnn + sN));
            float Hc = 1.f - 2.f / (e + 1.f);
            float Z  = 1.f / (1.f + __expf(-(xz + sZ)));
            float hnew = Z * hcv + (1.f - Z) * Hc;
            storet(hTb + n, hnew, (unsigned)(t + 1));  // publish FIRST
            __builtin_nontemporal_store(hnew, out + (size_t)t * BATCH * HDIM + bb32 + n);
            hcv = hnew;
            if (t == T_STEPS - 1)
                out[(size_t)T_STEPS * BATCH * HDIM + bb32 + n] = hnew;
        }
    }
}

extern "C" void kernel_launch(void* const* d_in, const int* in_sizes, int n_in,
                              void* d_out, int out_size, void* d_ws, size_t ws_size,
                              hipStream_t stream) {
    const float* inputs   = (const float*)d_in[0];
    const float* state    = (const float*)d_in[1];
    const float* W_reset  = (const float*)d_in[2];
    const float* b_reset  = (const float*)d_in[3];
    const float* W_net    = (const float*)d_in[4];
    const float* b_net    = (const float*)d_in[5];
    const float* W_update = (const float*)d_in[6];
    const float* b_update = (const float*)d_in[7];
    float* out = (float*)d_out;

    // ws layout: [xp chunk | packed Bt (1.5 MB) | tags (256 KB)]
    const size_t tag_bytes = 2ull * BATCH * HDIM * 8;
    const size_t bt_bytes  = 3ull * 64 * 512 * 8 * sizeof(_Float16);
    size_t tag_base = (ws_size - tag_bytes) & ~(size_t)255;
    size_t bt_base  = (tag_base - bt_bytes) & ~(size_t)255;
    char* base = (char*)d_ws;
    float*      xp = (float*)base;
    _Float16*   Bt = (_Float16*)(base + bt_base);
    unsigned long long* hT = (unsigned long long*)(base + tag_base);
    unsigned long long* uT = hT + (size_t)BATCH * HDIM;

    const size_t per_t = 3ull * BATCH * HDIM * sizeof(float);
    int C = (int)(bt_base / per_t);
    if (C > T_STEPS) C = T_STEPS;
    C &= ~3;                       // M divisible by BM=128
    if (C < 4) C = 4;

    hipMemsetAsync(hT, 0xFF, tag_bytes, stream);

    dim3 gp(64, 3);
    pack_b<<<gp, 512, 0, stream>>>(W_reset, W_net, W_update, Bt);

    for (int t0 = 0; t0 < T_STEPS; t0 += C) {
        const int nt = (T_STEPS - t0 < C) ? (T_STEPS - t0) : C;
        const int M  = nt * BATCH;

        dim3 g1(HDIM / BN, M / BM);
        xproj_mfma2<<<g1, 256, 0, stream>>>(inputs + (size_t)t0 * BATCH * VDIM,
                                            Bt, b_reset, b_net, b_update, xp, M);

        gru_scan6<<<BATCH * SLICES, 512, 0, stream>>>(
            xp,
            W_reset  + (size_t)VDIM * HDIM,
            W_net    + (size_t)VDIM * HDIM,
            W_update + (size_t)VDIM * HDIM,
            state, out, hT, uT, t0, nt, M);
    }
}